// Round 1
// baseline (1827.530 us; speedup 1.0000x reference)
//
#include <hip/hip_runtime.h>

// KMeans++ init on MI355X.
// B=32, N=16384, D=64, K=64. data: (B,N,D) fp32; first_idx: (B,) int32.
// Output centers: (B,K,D) fp32.
//
// Structure: 64 kernel launches (init + 63 steps). Kernel boundaries provide
// the grid-wide sync needed between argmax(min_d) and the min_d update.
// Grid: B*G blocks; each block owns N/G points of one batch.
// Partials (block-level argmax results) are double-buffered by step parity
// because blocks within one step kernel read the previous partials and write
// new ones concurrently.

#define B_  32
#define N_  16384
#define D_  64
#define K_  64
#define G_  16            // blocks per batch
#define T_  256           // threads per block
#define PPT 4             // points per thread = N_/(G_*T_)
#define CHUNK (N_ / G_)   // 1024 points per block

// numpy argmax semantics: first occurrence of the max -> on equal value,
// keep the smaller index.
__device__ __forceinline__ void amax_comb(float& v, int& i, float v2, int i2) {
    if (v2 > v || (v2 == v && i2 < i)) { v = v2; i = i2; }
}

// Block-wide argmax over (v,i) pairs; thread 0 writes the partial slot.
__device__ __forceinline__ void block_argmax_store(
    float v, int i, int b, int g, int parity,
    float* __restrict__ pval, int* __restrict__ pidx,
    float* red_v, int* red_i)
{
    #pragma unroll
    for (int off = 32; off > 0; off >>= 1) {
        float v2 = __shfl_down(v, off, 64);
        int   i2 = __shfl_down(i, off, 64);
        amax_comb(v, i, v2, i2);
    }
    int lane = threadIdx.x & 63;
    int wave = threadIdx.x >> 6;
    if (lane == 0) { red_v[wave] = v; red_i[wave] = i; }
    __syncthreads();
    if (threadIdx.x == 0) {
        #pragma unroll
        for (int w = 1; w < T_ / 64; ++w) amax_comb(v, i, red_v[w], red_i[w]);
        pval[(b * 2 + parity) * G_ + g] = v;
        pidx[(b * 2 + parity) * G_ + g] = i;
    }
}

// Distance of point row (float4*) to center staged in LDS (float4[16]).
__device__ __forceinline__ float dist2(const float4* __restrict__ row,
                                       const float4* csh)
{
    float ax = 0.f, ay = 0.f, az = 0.f, aw = 0.f;
    #pragma unroll
    for (int j = 0; j < D_ / 4; ++j) {
        float4 x = row[j];
        float4 c = csh[j];
        float dx = x.x - c.x, dy = x.y - c.y, dz = x.z - c.z, dw = x.w - c.w;
        ax = fmaf(dx, dx, ax);
        ay = fmaf(dy, dy, ay);
        az = fmaf(dz, dz, az);
        aw = fmaf(dw, dw, aw);
    }
    return (ax + ay) + (az + aw);   // fixed deterministic order
}

__global__ __launch_bounds__(T_) void kmpp_init(
    const float* __restrict__ data, const int* __restrict__ first_idx,
    float* __restrict__ min_d, float* __restrict__ pval, int* __restrict__ pidx,
    float* __restrict__ centers)
{
    const int blk = blockIdx.x;
    const int b = blk / G_, g = blk % G_;
    __shared__ float4 csh[D_ / 4];
    __shared__ float red_v[T_ / 64];
    __shared__ int   red_i[T_ / 64];

    const int ci = first_idx[b];
    const float4* crow = (const float4*)(data + ((size_t)b * N_ + ci) * D_);
    if (threadIdx.x < D_ / 4) csh[threadIdx.x] = crow[threadIdx.x];
    __syncthreads();
    if (g == 0 && threadIdx.x < D_ / 4)
        ((float4*)(centers + (size_t)b * K_ * D_))[threadIdx.x] = csh[threadIdx.x];

    float best_v = -1.f; int best_i = 0;
    for (int m = 0; m < PPT; ++m) {
        const int p = g * CHUNK + m * T_ + threadIdx.x;
        const float4* row = (const float4*)(data + ((size_t)b * N_ + p) * D_);
        float d = dist2(row, csh);
        min_d[(size_t)b * N_ + p] = d;
        amax_comb(best_v, best_i, d, p);
    }
    block_argmax_store(best_v, best_i, b, g, /*parity=*/0, pval, pidx, red_v, red_i);
}

__global__ __launch_bounds__(T_) void kmpp_step(
    const float* __restrict__ data, float* __restrict__ min_d,
    float* __restrict__ pval, int* __restrict__ pidx,
    float* __restrict__ centers, int k)
{
    const int blk = blockIdx.x;
    const int b = blk / G_, g = blk % G_;
    const int pin = (k - 1) & 1, pout = k & 1;
    __shared__ float4 csh[D_ / 4];
    __shared__ float red_v[T_ / 64];
    __shared__ int   red_i[T_ / 64];
    __shared__ int   sidx;

    if (threadIdx.x == 0) {
        float v = pval[(b * 2 + pin) * G_];
        int   i = pidx[(b * 2 + pin) * G_];
        for (int gg = 1; gg < G_; ++gg)
            amax_comb(v, i, pval[(b * 2 + pin) * G_ + gg], pidx[(b * 2 + pin) * G_ + gg]);
        sidx = i;
    }
    __syncthreads();
    const int ci = sidx;
    const float4* crow = (const float4*)(data + ((size_t)b * N_ + ci) * D_);
    if (threadIdx.x < D_ / 4) csh[threadIdx.x] = crow[threadIdx.x];
    __syncthreads();
    if (g == 0 && threadIdx.x < D_ / 4)
        ((float4*)(centers + ((size_t)b * K_ + k) * D_))[threadIdx.x] = csh[threadIdx.x];

    if (k == K_ - 1) return;   // last center: no further min_d/argmax needed

    float best_v = -1.f; int best_i = 0;
    for (int m = 0; m < PPT; ++m) {
        const int p = g * CHUNK + m * T_ + threadIdx.x;
        const float4* row = (const float4*)(data + ((size_t)b * N_ + p) * D_);
        float d = dist2(row, csh);
        const size_t off = (size_t)b * N_ + p;
        float nv = fminf(min_d[off], d);
        min_d[off] = nv;
        amax_comb(best_v, best_i, nv, p);
    }
    block_argmax_store(best_v, best_i, b, g, pout, pval, pidx, red_v, red_i);
}

extern "C" void kernel_launch(void* const* d_in, const int* in_sizes, int n_in,
                              void* d_out, int out_size, void* d_ws, size_t ws_size,
                              hipStream_t stream)
{
    const float* data      = (const float*)d_in[0];
    const int*   first_idx = (const int*)d_in[1];
    float*       centers   = (float*)d_out;

    // ws layout: min_d[B*N] | pval[B*2*G] | pidx[B*2*G]
    float* min_d = (float*)d_ws;
    float* pval  = min_d + (size_t)B_ * N_;
    int*   pidx  = (int*)(pval + B_ * 2 * G_);

    dim3 grid(B_ * G_), block(T_);
    hipLaunchKernelGGL(kmpp_init, grid, block, 0, stream,
                       data, first_idx, min_d, pval, pidx, centers);
    for (int k = 1; k < K_; ++k) {
        hipLaunchKernelGGL(kmpp_step, grid, block, 0, stream,
                           data, min_d, pval, pidx, centers, k);
    }
}